// Round 10
// baseline (249.313 us; speedup 1.0000x reference)
//
#include <hip/hip_runtime.h>
#include <hip/hip_bf16.h>

// Shapes are fixed by the problem definition.
#define B_   16
#define T_   4096
#define N_   512
#define D_   512
#define EPSF 1e-8f

typedef __attribute__((ext_vector_type(8))) short bf16x8; // 8 bf16 = 4 VGPRs
typedef __attribute__((ext_vector_type(4))) float f32x4;

// round-to-nearest-even f32 -> bf16, packed pair into one u32
__device__ __forceinline__ unsigned int pack2bf(float a, float b) {
  unsigned int ua = __float_as_uint(a);
  ua += 0x7fffu + ((ua >> 16) & 1u);
  unsigned int ub = __float_as_uint(b);
  ub += 0x7fffu + ((ub >> 16) & 1u);
  return (ua >> 16) | (ub & 0xffff0000u);
}

// async global->LDS, 16 B per lane
__device__ __forceinline__ void gload_lds16(const void* g, void* l) {
  __builtin_amdgcn_global_load_lds(
      (const __attribute__((address_space(1))) unsigned int*)g,
      (__attribute__((address_space(3))) unsigned int*)l, 16, 0, 0);
}

// ---------------------------------------------------------------------------
// Kernel A: distractor rows -> inv_nd (f32 norms) + bf16 copy (ydbf).
// ---------------------------------------------------------------------------
__global__ void rownorms_d(const float* __restrict__ yd,
                           float* __restrict__ inv_nd,
                           unsigned short* __restrict__ ydbf) {
  const int tid = threadIdx.x;
  const int g   = tid >> 4;
  const int t   = tid & 15;
  const int row = blockIdx.x * 16 + g;
  const float* dr = yd + (size_t)row * D_;
  unsigned short* ob = ydbf + (size_t)row * D_;

  float dd = 0.f;
#pragma unroll
  for (int k = 0; k < 8; ++k) {
    const int col = k * 64 + t * 4;
    float4 a = *(const float4*)(dr + col);
    dd += a.x * a.x + a.y * a.y + a.z * a.z + a.w * a.w;
    uint2 p;
    p.x = pack2bf(a.x, a.y);
    p.y = pack2bf(a.z, a.w);
    *(uint2*)(ob + col) = p;
  }
#pragma unroll
  for (int m = 1; m < 16; m <<= 1) dd += __shfl_xor(dd, m);
  if (t == 0) inv_nd[row] = 1.f / fmaxf(sqrtf(dd), EPSF);
}

// ---------------------------------------------------------------------------
// Kernel B (r10): fused stats+GEMM+exp in r2's PROVEN lean geometry.
// 2048 blocks (4 nt x 32 mt x 16 b), 256 thr / 4 waves (2x2), 128x128 tile,
// BK=64, As+Bs = 32 KB + 0.5 KB -> ~3 blocks/CU co-resident: independent
// barrier domains cover each other's staging drains (m114) — the mechanism
// every 1-2-domain mega-block (r4-r9, all 135-170 us) was missing.
// A reg-staged from f32 c (pack->bf16->LDS, r1-verified swizzle formula),
// yt rides along for cc/tt/ct register stats (full K per block -> local
// inv_nc; the 4 nt-blocks of a band compute stats redundantly; duplicate
// identical rt stores are benign). B via global_load_lds (r2-verbatim).
// XCD-chunked decode: XCD x owns bands x*64..x*64+63 (= 2 batches), with
// the 4 nt-blocks of a band consecutive -> c/yt redundancy is L2-local.
// ---------------------------------------------------------------------------
__launch_bounds__(256, 3)
__global__ void fused_ct(const float* __restrict__ c,
                         const float* __restrict__ yt,
                         const unsigned short* __restrict__ ydbf,
                         const float* __restrict__ inv_nd,
                         float* __restrict__ rt,
                         float* __restrict__ S) {
  __shared__ __align__(16) unsigned char As[128 * 64 * 2];  // 16 KB
  __shared__ __align__(16) unsigned char Bs[128 * 64 * 2];  // 16 KB
  __shared__ float s_invc[128];

  // decode (bijective: 2048 = 8 XCD x 64 bands x 4 nt)
  const int bid  = blockIdx.x;
  const int x    = bid & 7;
  const int k    = bid >> 3;            // 0..255
  const int band = x * 64 + (k >> 2);   // 0..511
  const int nt   = k & 3;
  const int b    = band >> 5;
  const int mt   = band & 31;

  const int tid  = threadIdx.x;
  const int lane = tid & 63;
  const int w    = tid >> 6;
  const int wm   = w >> 1, wn = w & 1;  // 2x2 waves over 128x128 out

  const float* Ab = c  + ((size_t)b * T_ + (size_t)mt * 128) * D_;
  const float* Tb = yt + ((size_t)b * T_ + (size_t)mt * 128) * D_;
  const unsigned short* Bb = ydbf + ((size_t)b * N_ + (size_t)nt * 128) * D_;

  float cc[8] = {}, tt[8] = {}, ct[8] = {};   // row j*16+(tid>>4), j=0..7
  f32x4 acc[4][4] = {};

  // ---- staging helpers (formulas verbatim from r1/r2, 0-conflict) ----
  auto stageB = [&](int k0) {
#pragma unroll
    for (int j = 0; j < 4; ++j) {
      const int g   = j * 256 + tid;        // chunk 0..1023 (16 B)
      const int row = g >> 3;               // 8 chunks per 64-bf16 row
      const int sch = (g & 7) ^ (row & 7);  // inverse-swizzled source chunk
      gload_lds16(Bb + (size_t)row * D_ + k0 + (sch << 3), Bs + (g << 4));
    }
  };
  // half = 0 -> rows 0..63 (stats slots 0..3), half = 1 -> rows 64..127
  auto stageA_half = [&](int k0, int half) {
    float4 va[4], vb[4];
#pragma unroll
    for (int j = 0; j < 4; ++j) {
      const int g   = (half * 4 + j) * 256 + tid;  // float4 0..2047
      const int row = g >> 4;
      const int c4  = g & 15;
      const size_t off = (size_t)row * D_ + k0 + (c4 << 2);
      va[j] = *(const float4*)(Ab + off);
      vb[j] = *(const float4*)(Tb + off);
    }
#pragma unroll
    for (int j = 0; j < 4; ++j) {
      const int g   = (half * 4 + j) * 256 + tid;
      const int row = g >> 4;
      const int c4  = g & 15;
      const int off = (row << 7) + ((((c4 >> 1) ^ (row & 7))) << 4) + ((c4 & 1) << 3);
      uint2 pa;
      pa.x = pack2bf(va[j].x, va[j].y);
      pa.y = pack2bf(va[j].z, va[j].w);
      *(uint2*)(As + off) = pa;
      const int sj = half * 4 + j;   // compile-time (half literal, j unrolled)
      cc[sj] += va[j].x * va[j].x + va[j].y * va[j].y + va[j].z * va[j].z + va[j].w * va[j].w;
      tt[sj] += vb[j].x * vb[j].x + vb[j].y * vb[j].y + vb[j].z * vb[j].z + vb[j].w * vb[j].w;
      ct[sj] += va[j].x * vb[j].x + va[j].y * vb[j].y + va[j].z * vb[j].z + va[j].w * vb[j].w;
    }
  };

  // ---- prologue: tile 0 ----
  stageB(0);
  stageA_half(0, 0);
  stageA_half(0, 1);
  __syncthreads();   // As visible; Bs gloads drained

  // ---- K-loop: 8 iters of BK=64, single-buffered (co-resident blocks
  //      cover the stage window) ----
  for (int t = 0; t < 8; ++t) {
#pragma unroll
    for (int ks = 0; ks < 2; ++ks) {
      bf16x8 af[4], bfr[4];
#pragma unroll
      for (int i = 0; i < 4; ++i) {
        const int ar  = wm * 64 + i * 16 + (lane & 15);
        const int ach = (ks * 4 + (lane >> 4)) ^ (ar & 7);
        af[i] = *(const bf16x8*)(As + (ar << 7) + (ach << 4));
        const int br  = wn * 64 + i * 16 + (lane & 15);
        const int bch = (ks * 4 + (lane >> 4)) ^ (br & 7);
        bfr[i] = *(const bf16x8*)(Bs + (br << 7) + (bch << 4));
      }
#pragma unroll
      for (int mi = 0; mi < 4; ++mi)
#pragma unroll
        for (int ni = 0; ni < 4; ++ni)
          acc[mi][ni] = __builtin_amdgcn_mfma_f32_16x16x32_bf16(
              af[mi], bfr[ni], acc[mi][ni], 0, 0, 0);
    }
    __syncthreads();                 // everyone done reading As/Bs
    if (t < 7) {
      stageB((t + 1) * 64);          // async; issued first to overlap VALU
      stageA_half((t + 1) * 64, 0);
      stageA_half((t + 1) * 64, 1);
      __syncthreads();               // drains gloads + ds_writes
    }
  }

  // ---- stats reduction: row j*16+(tid>>4), partials over c4=tid&15 ----
#pragma unroll
  for (int j = 0; j < 8; ++j) {
#pragma unroll
    for (int m = 1; m < 16; m <<= 1) {
      cc[j] += __shfl_xor(cc[j], m);
      tt[j] += __shfl_xor(tt[j], m);
      ct[j] += __shfl_xor(ct[j], m);
    }
    if ((tid & 15) == 0) {
      const int row = j * 16 + (tid >> 4);
      const float nc  = fmaxf(sqrtf(cc[j]), EPSF);
      const float ntv = fmaxf(sqrtf(tt[j]), EPSF);
      s_invc[row] = 1.f / nc;
      rt[b * T_ + mt * 128 + row] = ct[j] / (ntv * nc);  // dup across nt: benign
    }
  }
  __syncthreads();

  // ---- epilogue: exp(acc*invc*invd) row-sum, atomicAdd into S ----
  float invd[4];
#pragma unroll
  for (int ni = 0; ni < 4; ++ni)
    invd[ni] = inv_nd[b * N_ + nt * 128 + wn * 64 + ni * 16 + (lane & 15)];

#pragma unroll
  for (int mi = 0; mi < 4; ++mi) {
    const int rl0 = wm * 64 + mi * 16 + ((lane >> 4) << 2);  // local row
#pragma unroll
    for (int r = 0; r < 4; ++r) {
      const float invc = s_invc[rl0 + r];
      float s = 0.f;
#pragma unroll
      for (int ni = 0; ni < 4; ++ni)
        s += __expf(acc[mi][ni][r] * invc * invd[ni]);
      s += __shfl_xor(s, 1);
      s += __shfl_xor(s, 2);
      s += __shfl_xor(s, 4);
      s += __shfl_xor(s, 8);
      if ((lane & 15) == 0)
        atomicAdd(&S[b * T_ + mt * 128 + rl0 + r], s);
    }
  }
}

// ---------------------------------------------------------------------------
// Kernel C: loss = sum_{b,t} log(S + exp(r_t)) - r_t
// ---------------------------------------------------------------------------
__global__ void final_loss(const float* __restrict__ S,
                           const float* __restrict__ rt,
                           float* __restrict__ out) {
  const int tid = threadIdx.x;
  float sum = 0.f;
  for (int i = blockIdx.x * blockDim.x + tid; i < B_ * T_;
       i += gridDim.x * blockDim.x) {
    const float r = rt[i];
    sum += logf(S[i] + __expf(r)) - r;
  }
#pragma unroll
  for (int m = 32; m; m >>= 1) sum += __shfl_xor(sum, m);
  __shared__ float ws[4];
  if ((tid & 63) == 0) ws[tid >> 6] = sum;
  __syncthreads();
  if (tid == 0) atomicAdd(out, ws[0] + ws[1] + ws[2] + ws[3]);
}

// ---------------------------------------------------------------------------
extern "C" void kernel_launch(void* const* d_in, const int* in_sizes, int n_in,
                              void* d_out, int out_size, void* d_ws, size_t ws_size,
                              hipStream_t stream) {
  (void)in_sizes; (void)n_in; (void)out_size; (void)ws_size;
  const float* c  = (const float*)d_in[0];
  const float* yt = (const float*)d_in[1];
  const float* yd = (const float*)d_in[2];
  float* out = (float*)d_out;

  // ws layout: [ydbf: B*N*D u16][rt: B*T f][inv_nd: B*N f][S: B*T f]
  const size_t ydbf_n = (size_t)B_ * N_ * D_;   // 4.2M u16 = 8 MiB
  unsigned short* ydbf = (unsigned short*)d_ws;
  float* rt     = (float*)(ydbf + ydbf_n);      // B*T
  float* inv_nd = rt + B_ * T_;                 // B*N
  float* S      = inv_nd + B_ * N_;             // B*T

  hipMemsetAsync(S, 0, (size_t)B_ * T_ * sizeof(float), stream);
  hipMemsetAsync(out, 0, sizeof(float), stream);

  rownorms_d<<<B_ * N_ / 16, 256, 0, stream>>>(yd, inv_nd, ydbf);

  fused_ct<<<2048, 256, 0, stream>>>(c, yt, ydbf, inv_nd, rt, S);

  final_loss<<<64, 256, 0, stream>>>(S, rt, out);
}

// Round 11
// 91.883 us; speedup vs baseline: 2.7134x; 2.7134x over previous
//
#include <hip/hip_runtime.h>
#include <hip/hip_bf16.h>

// Shapes are fixed by the problem definition.
#define B_   16
#define T_   4096
#define N_   512
#define D_   512
#define EPSF 1e-8f

typedef __attribute__((ext_vector_type(8))) short bf16x8; // 8 bf16 = 4 VGPRs
typedef __attribute__((ext_vector_type(4))) float f32x4;

// round-to-nearest-even f32 -> bf16, packed pair into one u32
__device__ __forceinline__ unsigned int pack2bf(float a, float b) {
  unsigned int ua = __float_as_uint(a);
  ua += 0x7fffu + ((ua >> 16) & 1u);
  unsigned int ub = __float_as_uint(b);
  ub += 0x7fffu + ((ub >> 16) & 1u);
  return (ua >> 16) | (ub & 0xffff0000u);
}

// async global->LDS, 16 B per lane
__device__ __forceinline__ void gload_lds16(const void* g, void* l) {
  __builtin_amdgcn_global_load_lds(
      (const __attribute__((address_space(1))) unsigned int*)g,
      (__attribute__((address_space(3))) unsigned int*)l, 16, 0, 0);
}

// ---------------------------------------------------------------------------
// Kernel A: distractor rows -> inv_nd (f32 norms) + bf16 copy (ydbf).
// ---------------------------------------------------------------------------
__global__ void rownorms_d(const float* __restrict__ yd,
                           float* __restrict__ inv_nd,
                           unsigned short* __restrict__ ydbf) {
  const int tid = threadIdx.x;
  const int g   = tid >> 4;
  const int t   = tid & 15;
  const int row = blockIdx.x * 16 + g;
  const float* dr = yd + (size_t)row * D_;
  unsigned short* ob = ydbf + (size_t)row * D_;

  float dd = 0.f;
#pragma unroll
  for (int k = 0; k < 8; ++k) {
    const int col = k * 64 + t * 4;
    float4 a = *(const float4*)(dr + col);
    dd += a.x * a.x + a.y * a.y + a.z * a.z + a.w * a.w;
    uint2 p;
    p.x = pack2bf(a.x, a.y);
    p.y = pack2bf(a.z, a.w);
    *(uint2*)(ob + col) = p;
  }
#pragma unroll
  for (int m = 1; m < 16; m <<= 1) dd += __shfl_xor(dd, m);
  if (t == 0) inv_nd[row] = 1.f / fmaxf(sqrtf(dd), EPSF);
}

// B staging: r6-verbatim addressing (verified, 0 conflicts). 512x64 bf16.
__device__ __forceinline__ void stage_B(unsigned char* buf,
                                        const unsigned short* __restrict__ Bb,
                                        int k0, int tid) {
#pragma unroll
  for (int j = 0; j < 8; ++j) {
    const int g   = j * 512 + tid;          // chunk 0..4095 (16 B each)
    const int row = g >> 3;                 // 8 chunks per 64-bf16 row
    const int sch = (g & 7) ^ (row & 7);    // inverse-swizzled source chunk
    gload_lds16(Bb + (size_t)row * D_ + k0 + (sch << 3), buf + (g << 4));
  }
}

// A+T: issue 4 float4 of c and 4 float4 of yt into regs (early issue).
__device__ __forceinline__ void load_AT(const float* __restrict__ Ab,
                                        const float* __restrict__ Tb,
                                        int k0, int tid,
                                        float4* va, float4* vb) {
#pragma unroll
  for (int j = 0; j < 4; ++j) {
    const int g   = j * 512 + tid;          // float4 0..2047
    const int row = g >> 4;                 // 16 float4 per 64-col row
    const int c4  = g & 15;
    const size_t off = (size_t)row * D_ + k0 + (c4 << 2);
    va[j] = *(const float4*)(Ab + off);
    vb[j] = *(const float4*)(Tb + off);
  }
}

// cvt + swizzled LDS write of A (r1-verified formula) + stats accumulate.
__device__ __forceinline__ void writeA_stats(unsigned char* As,
                                             const float4* va, const float4* vb,
                                             int tid,
                                             float* cc, float* tt, float* ct) {
#pragma unroll
  for (int j = 0; j < 4; ++j) {
    const int g   = j * 512 + tid;
    const int row = g >> 4;
    const int c4  = g & 15;
    const int off = (row << 7) + ((((c4 >> 1) ^ (row & 7))) << 4) + ((c4 & 1) << 3);
    uint2 pa;
    pa.x = pack2bf(va[j].x, va[j].y);
    pa.y = pack2bf(va[j].z, va[j].w);
    *(uint2*)(As + off) = pa;
    cc[j] += va[j].x * va[j].x + va[j].y * va[j].y + va[j].z * va[j].z + va[j].w * va[j].w;
    tt[j] += vb[j].x * vb[j].x + vb[j].y * vb[j].y + vb[j].z * vb[j].z + vb[j].w * vb[j].w;
    ct[j] += va[j].x * vb[j].x + va[j].y * vb[j].y + va[j].z * vb[j].z + va[j].w * vb[j].w;
  }
}

// ---------------------------------------------------------------------------
// Kernel B (r11 = r6 + T3-minimum fix): one block per (mt,b) = 128 x N=512.
// r6's iteration was {compute; sync; stageB-issue; writeA(~100cy); sync} —
// the gload_lds burst drained one short window after issue (full HBM
// latency exposed). r11 issues stageB(t+1) BEFORE compute(t) (into the
// other Bs buffer), so the vmcnt(0) drain at the post-compute barrier
// lands after ~600 cycles of MFMA+ds_read (T3: "issue STAGE before
// ds_read+MFMA, not after"). Everything else r6-verbatim.
// ---------------------------------------------------------------------------
__launch_bounds__(512, 2)
__global__ void fused_ct(const float* __restrict__ c,
                         const float* __restrict__ yt,
                         const unsigned short* __restrict__ ydbf,
                         const float* __restrict__ inv_nd,
                         float* __restrict__ rt,
                         float* __restrict__ S) {
  __shared__ __align__(16) unsigned char As[128 * 64 * 2];       // 16 KB
  __shared__ __align__(16) unsigned char Bs[2][512 * 64 * 2];    // 2x64 KB
  __shared__ float s_invc[128];
  __shared__ float s_invd[512];

  const int mt = blockIdx.x;
  const int b  = blockIdx.y;
  const int tid  = threadIdx.x;
  const int lane = tid & 63;
  const int w    = tid >> 6;
  const int wm   = w >> 2, wn = w & 3;   // 2 x 4 waves over 128 x 512 out

  const float* Ab = c  + ((size_t)b * T_ + (size_t)mt * 128) * D_;
  const float* Tb = yt + ((size_t)b * T_ + (size_t)mt * 128) * D_;
  const unsigned short* Bb = ydbf + (size_t)b * N_ * D_;

  float4 va[4], vb[4];
  float cc[4] = {0.f, 0.f, 0.f, 0.f};
  float tt[4] = {0.f, 0.f, 0.f, 0.f};
  float ct[4] = {0.f, 0.f, 0.f, 0.f};

  // ---- prologue: iter-0 staging ----
  stage_B(Bs[0], Bb, 0, tid);            // async into Bs[0]
  load_AT(Ab, Tb, 0, tid, va, vb);
  s_invd[tid] = inv_nd[b * N_ + tid];
  writeA_stats(As, va, vb, tid, cc, tt, ct);
  __syncthreads();                       // As visible; Bs[0] gloads drained

  f32x4 acc[4][8] = {};

  // ---- K-loop: 8 iters of BK=64, double-buffered B, stage-before-compute --
  for (int k0i = 0; k0i < 8; ++k0i) {
    const bool more = (k0i < 7);
    if (more) {
      stage_B(Bs[(k0i + 1) & 1], Bb, (k0i + 1) * 64, tid);  // async, other buf
      load_AT(Ab, Tb, (k0i + 1) * 64, tid, va, vb);         // regs, early
    }

#pragma unroll
    for (int ks = 0; ks < 2; ++ks) {
      bf16x8 af[4], bfr[8];
#pragma unroll
      for (int i = 0; i < 4; ++i) {
        const int ar  = wm * 64 + i * 16 + (lane & 15);
        const int ach = (ks * 4 + (lane >> 4)) ^ (ar & 7);
        af[i] = *(const bf16x8*)(As + (ar << 7) + (ach << 4));
      }
#pragma unroll
      for (int n = 0; n < 8; ++n) {
        const int br  = wn * 128 + n * 16 + (lane & 15);
        const int bch = (ks * 4 + (lane >> 4)) ^ (br & 7);
        bfr[n] = *(const bf16x8*)(Bs[k0i & 1] + (br << 7) + (bch << 4));
      }
#pragma unroll
      for (int mi = 0; mi < 4; ++mi)
#pragma unroll
        for (int ni = 0; ni < 8; ++ni)
          acc[mi][ni] = __builtin_amdgcn_mfma_f32_16x16x32_bf16(
              af[mi], bfr[ni], acc[mi][ni], 0, 0, 0);
    }

    __syncthreads();   // drains stageB(t+1)+loadA(t+1) — hidden under compute
    if (more) {
      writeA_stats(As, va, vb, tid, cc, tt, ct);  // short VALU+LDS window
      __syncthreads();                            // As(t+1) visible
    }
  }

  // ---- stats reduction (16-lane groups; rows j*32+(tid>>4)) ----
#pragma unroll
  for (int j = 0; j < 4; ++j) {
#pragma unroll
    for (int m = 1; m < 16; m <<= 1) {
      cc[j] += __shfl_xor(cc[j], m);
      tt[j] += __shfl_xor(tt[j], m);
      ct[j] += __shfl_xor(ct[j], m);
    }
    if ((tid & 15) == 0) {
      const int row = j * 32 + (tid >> 4);
      const float nc = fmaxf(sqrtf(cc[j]), EPSF);
      const float nt = fmaxf(sqrtf(tt[j]), EPSF);
      s_invc[row] = 1.f / nc;
      rt[b * T_ + mt * 128 + row] = ct[j] / (nt * nc);
    }
  }
  __syncthreads();

  // ---- epilogue: exp(acc*invc*invd) row-sum over all 512 cols ----
  float invd[8];
#pragma unroll
  for (int ni = 0; ni < 8; ++ni)
    invd[ni] = s_invd[wn * 128 + ni * 16 + (lane & 15)];

#pragma unroll
  for (int mi = 0; mi < 4; ++mi) {
    const int t0l = wm * 64 + mi * 16 + ((lane >> 4) << 2);  // local row
#pragma unroll
    for (int r = 0; r < 4; ++r) {
      const float invc = s_invc[t0l + r];
      float s = 0.f;
#pragma unroll
      for (int ni = 0; ni < 8; ++ni)
        s += __expf(acc[mi][ni][r] * invc * invd[ni]);
      s += __shfl_xor(s, 1);
      s += __shfl_xor(s, 2);
      s += __shfl_xor(s, 4);
      s += __shfl_xor(s, 8);
      if ((lane & 15) == 0)
        atomicAdd(&S[b * T_ + mt * 128 + t0l + r], s);
    }
  }
}

// ---------------------------------------------------------------------------
// Kernel C: loss = sum_{b,t} log(S + exp(r_t)) - r_t
// ---------------------------------------------------------------------------
__global__ void final_loss(const float* __restrict__ S,
                           const float* __restrict__ rt,
                           float* __restrict__ out) {
  const int tid = threadIdx.x;
  float sum = 0.f;
  for (int i = blockIdx.x * blockDim.x + tid; i < B_ * T_;
       i += gridDim.x * blockDim.x) {
    const float r = rt[i];
    sum += logf(S[i] + __expf(r)) - r;
  }
#pragma unroll
  for (int m = 32; m; m >>= 1) sum += __shfl_xor(sum, m);
  __shared__ float ws[4];
  if ((tid & 63) == 0) ws[tid >> 6] = sum;
  __syncthreads();
  if (tid == 0) atomicAdd(out, ws[0] + ws[1] + ws[2] + ws[3]);
}

// ---------------------------------------------------------------------------
extern "C" void kernel_launch(void* const* d_in, const int* in_sizes, int n_in,
                              void* d_out, int out_size, void* d_ws, size_t ws_size,
                              hipStream_t stream) {
  (void)in_sizes; (void)n_in; (void)out_size; (void)ws_size;
  const float* c  = (const float*)d_in[0];
  const float* yt = (const float*)d_in[1];
  const float* yd = (const float*)d_in[2];
  float* out = (float*)d_out;

  // ws layout: [ydbf: B*N*D u16][rt: B*T f][inv_nd: B*N f][S: B*T f]
  const size_t ydbf_n = (size_t)B_ * N_ * D_;   // 4.2M u16 = 8 MiB
  unsigned short* ydbf = (unsigned short*)d_ws;
  float* rt     = (float*)(ydbf + ydbf_n);      // B*T
  float* inv_nd = rt + B_ * T_;                 // B*N
  float* S      = inv_nd + B_ * N_;             // B*T

  hipMemsetAsync(S, 0, (size_t)B_ * T_ * sizeof(float), stream);
  hipMemsetAsync(out, 0, sizeof(float), stream);

  rownorms_d<<<B_ * N_ / 16, 256, 0, stream>>>(yd, inv_nd, ydbf);

  dim3 gF(T_ / 128, B_);   // (32, 16) = 512 blocks, 512 threads
  fused_ct<<<gF, 512, 0, stream>>>(c, yt, ydbf, inv_nd, rt, S);

  final_loss<<<64, 256, 0, stream>>>(S, rt, out);
}